// Round 1
// baseline (153.543 us; speedup 1.0000x reference)
//
#include <hip/hip_runtime.h>

#define NTAGS 64
#define START_TAG 1
#define END_TAG 63

// ---------------------------------------------------------------------------
// Forward algorithm in the LINEAR domain:
//   p_t[j] = ( sum_i p_{t-1}[i] * expT[i][j] ) * exp(emit_t[j])
// with exact power-of-2 rescaling every 8 steps (exponent tracked in esum).
// One wave (64 lanes) per batch; lane j owns tag j and holds column j of expT
// in 64 VGPRs. Broadcast of p[i] is done with v_readlane (constant lane idx):
// no LDS, no barriers in the hot loop.
// ---------------------------------------------------------------------------
__global__ __launch_bounds__(64) void crf_forward(const float* __restrict__ feats,
                                                  const float* __restrict__ mask,
                                                  const float* __restrict__ trans,
                                                  float* __restrict__ fs, int S) {
    const int b = blockIdx.x;
    const int lane = threadIdx.x;

    // col[i] = exp(trans[i][lane])  (lane j holds column j)
    float col[NTAGS];
#pragma unroll
    for (int i = 0; i < NTAGS; ++i) col[i] = __expf(trans[i * NTAGS + lane]);

    const float* fb = feats + (size_t)b * S * NTAGS;
    const float* mb = mask + (size_t)b * S;

    // init: fv = NEG_INF except START_TAG=0  ->  p = one-hot(START_TAG)
    float p = (lane == START_TAG) ? 1.0f : 0.0f;
    int esum = 0;  // accumulated exponent (log-scale = esum * ln2)

    // double-buffered emit / mask for 8-step blocks
    float E[8], M[8];
#pragma unroll
    for (int u = 0; u < 8; ++u) E[u] = fb[u * NTAGS + lane];
    {
        float4 a = *reinterpret_cast<const float4*>(mb);
        float4 c = *reinterpret_cast<const float4*>(mb + 4);
        M[0] = a.x; M[1] = a.y; M[2] = a.z; M[3] = a.w;
        M[4] = c.x; M[5] = c.y; M[6] = c.z; M[7] = c.w;
    }

    for (int t0 = 0; t0 < S; t0 += 8) {
        float En[8], Mn[8];
        const bool more = (t0 + 8) < S;
        if (more) {
#pragma unroll
            for (int u = 0; u < 8; ++u) En[u] = fb[(t0 + 8 + u) * NTAGS + lane];
            float4 a = *reinterpret_cast<const float4*>(mb + t0 + 8);
            float4 c = *reinterpret_cast<const float4*>(mb + t0 + 12);
            Mn[0] = a.x; Mn[1] = a.y; Mn[2] = a.z; Mn[3] = a.w;
            Mn[4] = c.x; Mn[5] = c.y; Mn[6] = c.z; Mn[7] = c.w;
        }

#pragma unroll
        for (int u = 0; u < 8; ++u) {
            if (M[u] != 0.0f) {  // wave-uniform branch (mask value shared by all lanes)
                float a0 = 0.f, a1 = 0.f, a2 = 0.f, a3 = 0.f;
#pragma unroll
                for (int i = 0; i < NTAGS; i += 4) {
                    float s0 = __uint_as_float(__builtin_amdgcn_readlane(__float_as_uint(p), i + 0));
                    float s1 = __uint_as_float(__builtin_amdgcn_readlane(__float_as_uint(p), i + 1));
                    float s2 = __uint_as_float(__builtin_amdgcn_readlane(__float_as_uint(p), i + 2));
                    float s3 = __uint_as_float(__builtin_amdgcn_readlane(__float_as_uint(p), i + 3));
                    a0 = fmaf(s0, col[i + 0], a0);
                    a1 = fmaf(s1, col[i + 1], a1);
                    a2 = fmaf(s2, col[i + 2], a2);
                    a3 = fmaf(s3, col[i + 3], a3);
                }
                float nv = (a0 + a1) + (a2 + a3);
                p = nv * __expf(E[u]);
            }
        }

        // exact power-of-2 rescale (semantics-neutral, keeps f32 in range)
        float mx = p;
#pragma unroll
        for (int sh = 32; sh >= 1; sh >>= 1) mx = fmaxf(mx, __shfl_xor(mx, sh));
        int ex;
        (void)frexpf(mx, &ex);  // mx = f * 2^ex, f in [0.5,1); mx > 0 always
        p = ldexpf(p, -ex);
        esum += ex;

        if (more) {
#pragma unroll
            for (int u = 0; u < 8; ++u) { E[u] = En[u]; M[u] = Mn[u]; }
        }
    }

    // terminal: forward = log( sum_j p[j] * exp(T[j][END]) ) + esum*ln2
    float term = p * __expf(trans[lane * NTAGS + END_TAG]);
#pragma unroll
    for (int sh = 32; sh >= 1; sh >>= 1) term += __shfl_xor(term, sh);
    if (lane == 0) fs[b] = logf(term) + (float)esum * 0.69314718055994530942f;
}

// ---------------------------------------------------------------------------
// Gold path score: sum_t (feats[b,t,tags[t]] + T[prev,cur]) * mask[t]
//                  + T[last_tag, END]
// One wave per batch, lanes stride over t.
// ---------------------------------------------------------------------------
__global__ __launch_bounds__(64) void crf_gold(const float* __restrict__ feats,
                                               const float* __restrict__ mask,
                                               const int* __restrict__ tags,
                                               const float* __restrict__ trans,
                                               float* __restrict__ gs, int S) {
    const int b = blockIdx.x;
    const int lane = threadIdx.x;
    const float* fb = feats + (size_t)b * S * NTAGS;
    const float* mb = mask + (size_t)b * S;
    const int* tb = tags + (size_t)b * S;

    float acc = 0.f, msum = 0.f;
    for (int t = lane; t < S; t += 64) {
        int cur = tb[t];
        int prev = (t == 0) ? START_TAG : tb[t - 1];
        float m = mb[t];
        acc += (fb[t * NTAGS + cur] + trans[prev * NTAGS + cur]) * m;
        msum += m;
    }
#pragma unroll
    for (int sh = 32; sh >= 1; sh >>= 1) {
        acc += __shfl_xor(acc, sh);
        msum += __shfl_xor(msum, sh);
    }
    if (lane == 0) {
        int seq_end = (int)(msum + 0.5f) - 1;
        int last = (seq_end >= 0) ? tb[seq_end] : START_TAG;
        gs[b] = acc + trans[last * NTAGS + END_TAG];
    }
}

// ---------------------------------------------------------------------------
// out = mean_b (fs[b] - gs[b])
// ---------------------------------------------------------------------------
__global__ void crf_reduce(const float* __restrict__ fs, const float* __restrict__ gs,
                           float* __restrict__ out, int B) {
    const int tid = threadIdx.x;  // 256 threads
    float a = 0.f;
    for (int i = tid; i < B; i += 256) a += fs[i] - gs[i];
#pragma unroll
    for (int sh = 32; sh >= 1; sh >>= 1) a += __shfl_xor(a, sh);
    __shared__ float buf[4];
    if ((tid & 63) == 0) buf[tid >> 6] = a;
    __syncthreads();
    if (tid == 0) out[0] = (buf[0] + buf[1] + buf[2] + buf[3]) / (float)B;
}

extern "C" void kernel_launch(void* const* d_in, const int* in_sizes, int n_in,
                              void* d_out, int out_size, void* d_ws, size_t ws_size,
                              hipStream_t stream) {
    const float* feats = (const float*)d_in[0];
    const float* mask  = (const float*)d_in[1];
    const int*   tags  = (const int*)d_in[2];
    const float* trans = (const float*)d_in[3];
    float* out = (float*)d_out;

    const int S = 512;                 // reference shape
    const int B = in_sizes[1] / S;     // mask is (B,S)

    float* fs = (float*)d_ws;
    float* gs = fs + B;

    crf_forward<<<B, 64, 0, stream>>>(feats, mask, trans, fs, S);
    crf_gold<<<B, 64, 0, stream>>>(feats, mask, tags, trans, gs, S);
    crf_reduce<<<1, 256, 0, stream>>>(fs, gs, out, B);
}

// Round 2
// 107.757 us; speedup vs baseline: 1.4249x; 1.4249x over previous
//
#include <hip/hip_runtime.h>

#define NTAGS 64
#define START_TAG 1
#define END_TAG 63
#define LN2F 0.69314718055994530942f

typedef float v2f __attribute__((ext_vector_type(2)));
typedef float v4f __attribute__((ext_vector_type(4)));

static __device__ __forceinline__ v2f pkfma(v2f a, v2f b, v2f c) {
    return __builtin_elementwise_fma(a, b, c);
}
static __device__ __forceinline__ v2f pkmax(v2f a, v2f b) {
    return __builtin_elementwise_max(a, b);
}

// ---------------------------------------------------------------------------
// Fused forward-algorithm (blocks [0,B)) + gold-score (blocks [B,2B)).
//
// Forward: linear-domain recursion p_t = (p_{t-1}^T expT) .* exp(emit_t),
// exact power-of-2 rescale every 8 steps (exponent in esum). One wave per
// batch. Broadcast of the p-vector is via LDS: 1 stride-1 ds_write + 16
// uniform-address ds_read_b128 (broadcast, conflict-free) into 64 VGPRs per
// lane; the 64-term dot product is then 32 v_pk_fma_f32 with no SGPR hazards.
// The rescale max is computed from the in-register copy (lag-1, bound-safe).
// ---------------------------------------------------------------------------
__global__ __launch_bounds__(64) void crf_fused(const float* __restrict__ feats,
                                                const float* __restrict__ mask,
                                                const int* __restrict__ tags,
                                                const float* __restrict__ trans,
                                                float* __restrict__ fs,
                                                float* __restrict__ gs,
                                                int S, int B) {
    const int lane = threadIdx.x;

    if ((int)blockIdx.x >= B) {
        // ---- gold path score: one wave per batch, lanes stride over t ----
        const int b = (int)blockIdx.x - B;
        const float* fb = feats + (size_t)b * S * NTAGS;
        const float* mb = mask + (size_t)b * S;
        const int* tb = tags + (size_t)b * S;

        float acc = 0.f, msum = 0.f;
        for (int t = lane; t < S; t += 64) {
            int cur = tb[t];
            int prev = (t == 0) ? START_TAG : tb[t - 1];
            float m = mb[t];
            acc += (fb[t * NTAGS + cur] + trans[prev * NTAGS + cur]) * m;
            msum += m;
        }
#pragma unroll
        for (int sh = 32; sh >= 1; sh >>= 1) {
            acc += __shfl_xor(acc, sh);
            msum += __shfl_xor(msum, sh);
        }
        if (lane == 0) {
            int seq_end = (int)(msum + 0.5f) - 1;
            int last = (seq_end >= 0) ? tb[seq_end] : START_TAG;
            gs[b] = acc + trans[last * NTAGS + END_TAG];
        }
        return;
    }

    // ---- forward algorithm ----
    __shared__ __align__(16) float pl[NTAGS];
    const int b = (int)blockIdx.x;
    const float* fb = feats + (size_t)b * S * NTAGS;
    const float* mb = mask + (size_t)b * S;

    // c[i2] = { exp(T[2*i2][lane]), exp(T[2*i2+1][lane]) }  (lane owns col lane)
    v2f c[NTAGS / 2];
#pragma unroll
    for (int i = 0; i < NTAGS / 2; ++i) {
        c[i].x = __expf(trans[(2 * i) * NTAGS + lane]);
        c[i].y = __expf(trans[(2 * i + 1) * NTAGS + lane]);
    }

    float p = (lane == START_TAG) ? 1.0f : 0.0f;
    pl[lane] = p;
    int esum = 0;

    // E holds exp(emit) (pre-exponentiated off the critical path); M holds mask
    float E[8], M[8];
#pragma unroll
    for (int u = 0; u < 8; ++u) E[u] = __expf(fb[u * NTAGS + lane]);
    {
        v4f a = *(const v4f*)(mb);
        v4f d = *(const v4f*)(mb + 4);
        M[0] = a.x; M[1] = a.y; M[2] = a.z; M[3] = a.w;
        M[4] = d.x; M[5] = d.y; M[6] = d.z; M[7] = d.w;
    }

    v4f q[16];  // in-register copy of the full p-vector (refreshed each step)

    for (int t0 = 0; t0 < S; t0 += 8) {
        float En[8];
        v4f Ma, Mb2;
        const bool more = (t0 + 8) < S;
        if (more) {
#pragma unroll
            for (int u = 0; u < 8; ++u) En[u] = fb[(size_t)(t0 + 8 + u) * NTAGS + lane];
            Ma  = *(const v4f*)(mb + t0 + 8);
            Mb2 = *(const v4f*)(mb + t0 + 12);
        }

#pragma unroll
        for (int u = 0; u < 8; ++u) {
            // broadcast whole p-vector: 16 uniform-address ds_read_b128
#pragma unroll
            for (int r = 0; r < 16; ++r) q[r] = ((const v4f*)pl)[r];

            v2f a0 = {0.f, 0.f}, a1 = a0, a2 = a0, a3 = a0;
#pragma unroll
            for (int r = 0; r < 16; r += 2) {
                a0 = pkfma(q[r].lo,     c[2 * r],     a0);
                a1 = pkfma(q[r].hi,     c[2 * r + 1], a1);
                a2 = pkfma(q[r + 1].lo, c[2 * r + 2], a2);
                a3 = pkfma(q[r + 1].hi, c[2 * r + 3], a3);
            }
            v2f s = (a0 + a1) + (a2 + a3);
            float nv = s.x + s.y;
            float pn = nv * E[u];
            p = (M[u] != 0.0f) ? pn : p;  // per-lane select; mask value is uniform
            pl[lane] = p;                 // publish for next step (in-order DS)
        }

        // exact power-of-2 rescale every 8 steps, using the lag-1 register
        // copy (q = p_{t0+6}); one-step growth is bounded, so 9 steps between
        // exponent resets stays far below f32 overflow.
        {
            v2f t8[8];
#pragma unroll
            for (int r = 0; r < 8; ++r)
                t8[r] = pkmax(pkmax(q[r].lo, q[r].hi), pkmax(q[r + 8].lo, q[r + 8].hi));
            v2f t4a = pkmax(t8[0], t8[4]), t4b = pkmax(t8[1], t8[5]);
            v2f t4c = pkmax(t8[2], t8[6]), t4d = pkmax(t8[3], t8[7]);
            v2f t2 = pkmax(pkmax(t4a, t4b), pkmax(t4c, t4d));
            float mx = fmaxf(t2.x, t2.y);  // identical in every lane
            int ex;
            (void)frexpf(mx, &ex);
            p = ldexpf(p, -ex);
            esum += ex;
            pl[lane] = p;
        }

        if (more) {
#pragma unroll
            for (int u = 0; u < 8; ++u) E[u] = __expf(En[u]);
            M[0] = Ma.x;  M[1] = Ma.y;  M[2] = Ma.z;  M[3] = Ma.w;
            M[4] = Mb2.x; M[5] = Mb2.y; M[6] = Mb2.z; M[7] = Mb2.w;
        }
    }

    // terminal: forward = log( sum_j p[j] * exp(T[j][END]) ) + esum*ln2
    float term = p * __expf(trans[lane * NTAGS + END_TAG]);
#pragma unroll
    for (int sh = 32; sh >= 1; sh >>= 1) term += __shfl_xor(term, sh);
    if (lane == 0) fs[b] = logf(term) + (float)esum * LN2F;
}

// ---------------------------------------------------------------------------
// out = mean_b (fs[b] - gs[b])
// ---------------------------------------------------------------------------
__global__ void crf_reduce(const float* __restrict__ fs, const float* __restrict__ gs,
                           float* __restrict__ out, int B) {
    const int tid = threadIdx.x;  // 256 threads
    float a = 0.f;
    for (int i = tid; i < B; i += 256) a += fs[i] - gs[i];
#pragma unroll
    for (int sh = 32; sh >= 1; sh >>= 1) a += __shfl_xor(a, sh);
    __shared__ float buf[4];
    if ((tid & 63) == 0) buf[tid >> 6] = a;
    __syncthreads();
    if (tid == 0) out[0] = (buf[0] + buf[1] + buf[2] + buf[3]) / (float)B;
}

extern "C" void kernel_launch(void* const* d_in, const int* in_sizes, int n_in,
                              void* d_out, int out_size, void* d_ws, size_t ws_size,
                              hipStream_t stream) {
    const float* feats = (const float*)d_in[0];
    const float* mask  = (const float*)d_in[1];
    const int*   tags  = (const int*)d_in[2];
    const float* trans = (const float*)d_in[3];
    float* out = (float*)d_out;

    const int S = 512;              // reference shape
    const int B = in_sizes[1] / S;  // mask is (B,S)

    float* fs = (float*)d_ws;
    float* gs = fs + B;

    crf_fused<<<2 * B, 64, 0, stream>>>(feats, mask, tags, trans, fs, gs, S, B);
    crf_reduce<<<1, 256, 0, stream>>>(fs, gs, out, B);
}

// Round 3
// 87.907 us; speedup vs baseline: 1.7466x; 1.2258x over previous
//
#include <hip/hip_runtime.h>

#define NTAGS 64
#define START_TAG 1
#define END_TAG 63
#define LN2F 0.69314718055994530942f

typedef float v2f __attribute__((ext_vector_type(2)));
typedef float v4f __attribute__((ext_vector_type(4)));

static __device__ __forceinline__ v2f pkfma(v2f a, v2f b, v2f c) {
    return __builtin_elementwise_fma(a, b, c);
}
static __device__ __forceinline__ v2f pkmax(v2f a, v2f b) {
    return __builtin_elementwise_max(a, b);
}

// 64-term dot of the LDS-broadcast vector q[] against per-lane coeffs c[],
// returns scalar sum. 16 uniform-address ds_read_b128 (broadcast,
// conflict-free) + 32 v_pk_fma_f32, no cross-lane ops.
static __device__ __forceinline__ float dot64(const float* pl, const v2f* c, v4f* q) {
#pragma unroll
    for (int r = 0; r < 16; ++r) q[r] = ((const v4f*)pl)[r];
    v2f a0 = {0.f, 0.f}, a1 = a0, a2 = a0, a3 = a0;
#pragma unroll
    for (int r = 0; r < 16; r += 2) {
        a0 = pkfma(q[r].lo,     c[2 * r],     a0);
        a1 = pkfma(q[r].hi,     c[2 * r + 1], a1);
        a2 = pkfma(q[r + 1].lo, c[2 * r + 2], a2);
        a3 = pkfma(q[r + 1].hi, c[2 * r + 3], a3);
    }
    v2f s = (a0 + a1) + (a2 + a3);
    return s.x + s.y;
}

// exact power-of-2 rescale factor from the lag-1 register copy q[]
static __device__ __forceinline__ int exp_of_max(const v4f* q) {
    v2f t8[8];
#pragma unroll
    for (int r = 0; r < 8; ++r)
        t8[r] = pkmax(pkmax(q[r].lo, q[r].hi), pkmax(q[r + 8].lo, q[r + 8].hi));
    v2f t4a = pkmax(t8[0], t8[4]), t4b = pkmax(t8[1], t8[5]);
    v2f t4c = pkmax(t8[2], t8[6]), t4d = pkmax(t8[3], t8[7]);
    v2f t2 = pkmax(pkmax(t4a, t4b), pkmax(t4c, t4d));
    float mx = fmaxf(t2.x, t2.y);  // identical in every lane
    int ex;
    (void)frexpf(mx, &ex);
    return ex;
}

// ---------------------------------------------------------------------------
// Fused kernel, 3B blocks of one wave each:
//   blocks [0,B):    forward half-chain  z = M_{H-1}...M_0 p0      (t=0..H-1)
//   blocks [B,2B):   backward half-chain w = M_H^T...M_{S-1}^T u   (t=S-1..H)
//   blocks [2B,3B):  gold path score
// M_t = mask_t ? diag(exp(emit_t)) expT^T : I ;  u[j] = exp(T[j,END]).
// Linear domain with exact power-of-2 rescale every 8 steps.
// forward_score[b] = log(w.z) + (ez+ew)*ln2  (combine kernel).
// ---------------------------------------------------------------------------
__global__ __launch_bounds__(64) void crf_fused(const float* __restrict__ feats,
                                                const float* __restrict__ mask,
                                                const int* __restrict__ tags,
                                                const float* __restrict__ trans,
                                                float* __restrict__ zv,
                                                float* __restrict__ wv,
                                                float* __restrict__ gs,
                                                int* __restrict__ ez,
                                                int* __restrict__ ew,
                                                int S, int H, int B) {
    const int lane = threadIdx.x;
    const int bid = (int)blockIdx.x;

    if (bid >= 2 * B) {
        // ---- gold path score ----
        const int b = bid - 2 * B;
        const float* fb = feats + (size_t)b * S * NTAGS;
        const float* mb = mask + (size_t)b * S;
        const int* tb = tags + (size_t)b * S;

        float acc = 0.f, msum = 0.f;
        for (int t = lane; t < S; t += 64) {
            int cur = tb[t];
            int prev = (t == 0) ? START_TAG : tb[t - 1];
            float m = mb[t];
            acc += (fb[t * NTAGS + cur] + trans[prev * NTAGS + cur]) * m;
            msum += m;
        }
#pragma unroll
        for (int sh = 32; sh >= 1; sh >>= 1) {
            acc += __shfl_xor(acc, sh);
            msum += __shfl_xor(msum, sh);
        }
        if (lane == 0) {
            int seq_end = (int)(msum + 0.5f) - 1;
            int last = (seq_end >= 0) ? tb[seq_end] : START_TAG;
            gs[b] = acc + trans[last * NTAGS + END_TAG];
        }
        return;
    }

    __shared__ __align__(16) float pl[NTAGS];
    v4f q[16];
    v2f c[NTAGS / 2];

    if (bid < B) {
        // ---- forward half: lane j owns tag j, holds column j of expT ----
        const int b = bid;
        const float* fb = feats + (size_t)b * S * NTAGS;
        const float* mb = mask + (size_t)b * S;
#pragma unroll
        for (int i = 0; i < NTAGS / 2; ++i) {
            c[i].x = __expf(trans[(2 * i) * NTAGS + lane]);
            c[i].y = __expf(trans[(2 * i + 1) * NTAGS + lane]);
        }

        float p = (lane == START_TAG) ? 1.0f : 0.0f;
        pl[lane] = p;
        int esum = 0;

        float E[8], M[8];
#pragma unroll
        for (int u = 0; u < 8; ++u) E[u] = __expf(fb[u * NTAGS + lane]);
        {
            v4f a = *(const v4f*)(mb);
            v4f d = *(const v4f*)(mb + 4);
            M[0] = a.x; M[1] = a.y; M[2] = a.z; M[3] = a.w;
            M[4] = d.x; M[5] = d.y; M[6] = d.z; M[7] = d.w;
        }

        for (int t0 = 0; t0 < H; t0 += 8) {
            float En[8];
            v4f Ma, Mb2;
            const bool more = (t0 + 8) < H;
            if (more) {
#pragma unroll
                for (int u = 0; u < 8; ++u) En[u] = fb[(size_t)(t0 + 8 + u) * NTAGS + lane];
                Ma  = *(const v4f*)(mb + t0 + 8);
                Mb2 = *(const v4f*)(mb + t0 + 12);
            }

#pragma unroll
            for (int u = 0; u < 8; ++u) {
                float nv = dot64(pl, c, q);
                float pn = nv * E[u];
                p = (M[u] != 0.0f) ? pn : p;
                pl[lane] = p;
            }

            int ex = exp_of_max(q);
            p = ldexpf(p, -ex);
            esum += ex;
            pl[lane] = p;

            if (more) {
#pragma unroll
                for (int u = 0; u < 8; ++u) E[u] = __expf(En[u]);
                M[0] = Ma.x;  M[1] = Ma.y;  M[2] = Ma.z;  M[3] = Ma.w;
                M[4] = Mb2.x; M[5] = Mb2.y; M[6] = Mb2.z; M[7] = Mb2.w;
            }
        }

        zv[(size_t)b * NTAGS + lane] = p;
        if (lane == 0) ez[b] = esum;
    } else {
        // ---- backward half: lane i owns tag i, holds ROW i of expT ----
        // w_{t-1} = mask_t ? expT (E_t .* w_t) : w_t, t = S-1 .. H
        const int b = bid - B;
        const float* fb = feats + (size_t)b * S * NTAGS;
        const float* mb = mask + (size_t)b * S;
#pragma unroll
        for (int i = 0; i < NTAGS / 2; ++i) {
            c[i].x = __expf(trans[lane * NTAGS + 2 * i]);
            c[i].y = __expf(trans[lane * NTAGS + 2 * i + 1]);
        }

        float w = __expf(trans[lane * NTAGS + END_TAG]);  // u
        int esum = 0;
        const int NB = S - H;  // number of backward steps

        float E[8], M[8];
#pragma unroll
        for (int u = 0; u < 8; ++u) E[u] = __expf(fb[(size_t)(S - 1 - u) * NTAGS + lane]);
#pragma unroll
        for (int u = 0; u < 8; ++u) M[u] = mb[S - 1 - u];

        for (int t0 = 0; t0 < NB; t0 += 8) {
            float En[8], Mn[8];
            const bool more = (t0 + 8) < NB;
            if (more) {
#pragma unroll
                for (int u = 0; u < 8; ++u)
                    En[u] = fb[(size_t)(S - 1 - (t0 + 8 + u)) * NTAGS + lane];
#pragma unroll
                for (int u = 0; u < 8; ++u) Mn[u] = mb[S - 1 - (t0 + 8 + u)];
            }

#pragma unroll
            for (int u = 0; u < 8; ++u) {
                pl[lane] = w * E[u];          // publish y = E .* w
                float nv = dot64(pl, c, q);   // q = y (lag copy for rescale)
                w = (M[u] != 0.0f) ? nv : w;
            }

            int ex = exp_of_max(q);
            w = ldexpf(w, -ex);
            esum += ex;

            if (more) {
#pragma unroll
                for (int u = 0; u < 8; ++u) { E[u] = __expf(En[u]); M[u] = Mn[u]; }
            }
        }

        wv[(size_t)b * NTAGS + lane] = w;
        if (lane == 0) ew[b] = esum;
    }
}

// ---------------------------------------------------------------------------
// combine + mean: out = mean_b( log(z_b . w_b) + (ez+ew)*ln2 - gs_b )
// ---------------------------------------------------------------------------
__global__ __launch_bounds__(1024) void crf_combine(const float* __restrict__ zv,
                                                    const float* __restrict__ wv,
                                                    const float* __restrict__ gs,
                                                    const int* __restrict__ ez,
                                                    const int* __restrict__ ew,
                                                    float* __restrict__ out, int B) {
    const int tid = threadIdx.x;
    const int wave = tid >> 6, lane = tid & 63;
    float local = 0.f;
    for (int b = wave; b < B; b += 16) {
        float s = zv[(size_t)b * NTAGS + lane] * wv[(size_t)b * NTAGS + lane];
#pragma unroll
        for (int sh = 32; sh >= 1; sh >>= 1) s += __shfl_xor(s, sh);
        if (lane == 0)
            local += logf(s) + (float)(ez[b] + ew[b]) * LN2F - gs[b];
    }
    __shared__ float buf[16];
    if (lane == 0) buf[wave] = local;
    __syncthreads();
    if (tid == 0) {
        float a = 0.f;
#pragma unroll
        for (int i = 0; i < 16; ++i) a += buf[i];
        out[0] = a / (float)B;
    }
}

extern "C" void kernel_launch(void* const* d_in, const int* in_sizes, int n_in,
                              void* d_out, int out_size, void* d_ws, size_t ws_size,
                              hipStream_t stream) {
    const float* feats = (const float*)d_in[0];
    const float* mask  = (const float*)d_in[1];
    const int*   tags  = (const int*)d_in[2];
    const float* trans = (const float*)d_in[3];
    float* out = (float*)d_out;

    const int S = 512;              // reference shape
    const int B = in_sizes[1] / S;  // mask is (B,S)
    const int H = S / 2;

    float* zv = (float*)d_ws;
    float* wv = zv + (size_t)B * NTAGS;
    float* gs = wv + (size_t)B * NTAGS;
    int* ez = (int*)(gs + B);
    int* ew = ez + B;

    crf_fused<<<3 * B, 64, 0, stream>>>(feats, mask, tags, trans, zv, wv, gs, ez, ew, S, H, B);
    crf_combine<<<1, 1024, 0, stream>>>(zv, wv, gs, ez, ew, out, B);
}